// Round 9
// baseline (2873.690 us; speedup 1.0000x reference)
//
#include <hip/hip_runtime.h>
#include <stdint.h>

typedef __attribute__((ext_vector_type(4))) float f32x4;
typedef __attribute__((ext_vector_type(8))) short bf16x8;

#define MFMA_BF16 __builtin_amdgcn_mfma_f32_16x16x32_bf16

__device__ __forceinline__ unsigned short f2bf(float f) {
  union { float f; uint32_t u; } a; a.f = f;
  uint32_t u = a.u;
  uint32_t r = (u + 0x7FFFu + ((u >> 16) & 1u)) >> 16;
  return (unsigned short)r;
}

// Merged pack: quads 0..4194303 = A ([x|h] -> bf16 A[4096][4096]);
// quads 4194304..12582911 = W (8 mats -> gate-interleaved Wp[8192][4096]).
__global__ void pack_all_kernel(const float4* __restrict__ x, const float4* __restrict__ hh,
                                const float* __restrict__ Wii, const float* __restrict__ Wif,
                                const float* __restrict__ Wig, const float* __restrict__ Wio,
                                const float* __restrict__ Whi, const float* __restrict__ Whf,
                                const float* __restrict__ Whg, const float* __restrict__ Who,
                                ushort4* __restrict__ A, ushort4* __restrict__ Wp) {
  const int total = 12582912;
  for (int q = blockIdx.x * blockDim.x + threadIdx.x; q < total; q += gridDim.x * blockDim.x) {
    if (q < 4194304) {
      int row = q >> 10, cq = q & 1023;
      float4 v = (cq < 512) ? x[row * 512 + cq] : hh[row * 512 + (cq - 512)];
      ushort4 o; o.x = f2bf(v.x); o.y = f2bf(v.y); o.z = f2bf(v.z); o.w = f2bf(v.w);
      A[q] = o;
    } else {
      int wq = q - 4194304;
      int p = wq >> 10, kq = wq & 1023;
      int r = p & 255;
      int g = ((r >> 7) << 1) | ((r >> 4) & 1);
      int H = ((p >> 8) << 6) | (((r >> 5) & 3) << 4) | (r & 15);
      const float* src;
      if (kq < 512) src = (g == 0) ? Wii : (g == 1) ? Wif : (g == 2) ? Wig : Wio;
      else          src = (g == 0) ? Whi : (g == 1) ? Whf : (g == 2) ? Whg : Who;
      const float4 v = *(const float4*)&src[(size_t)H * 2048 + ((kq & 511) << 2)];
      ushort4 o; o.x = f2bf(v.x); o.y = f2bf(v.y); o.z = f2bf(v.z); o.w = f2bf(v.w);
      Wp[wq] = o;
    }
  }
}

// 256x256 tile, BK=32, 8 waves (2Mx4N), per-wave 128x64, 4-deep LDS ring.
// Register double-buffered fragments (PREF tile T+1 during tile T).
// PARITY STAGGER: waves 0-3 do PREF->COMP, waves 4-7 do COMP->PREF (SIMD
// partners w and w+4 de-phase LDS pipe vs MFMA pipe).
// Barrier + vmcnt(0) every TWO tiles (ring-4 makes this safe).
#define GLD(srcp, dstE)                                                         \
  __builtin_amdgcn_global_load_lds(                                             \
      (const __attribute__((address_space(1))) void*)(srcp),                    \
      (__attribute__((address_space(3))) void*)(&smem[dstE]), 16, 0, 0)

#define STAGE_R(t_, ringB_)                                                     \
  {                                                                             \
    const size_t kO_ = (size_t)(t_) * 32;                                       \
    GLD(aS + kO_, (ringB_) + dA);                                               \
    GLD(aS + 524288 + kO_, (ringB_) + dA + 4096);                               \
    GLD(bS + kO_, (ringB_) + dB);                                               \
    GLD(bS + 524288 + kO_, (ringB_) + dB + 4096);                               \
  }

#define PREF(RN_, AF_, BF_)                                                     \
  {                                                                             \
    _Pragma("unroll") for (int n = 0; n < 4; ++n)                               \
      BF_[n] = *(const bf16x8*)&smem[(RN_) + bRB + (n >> 1) * 4096 + (n & 1) * 512]; \
    _Pragma("unroll") for (int m = 0; m < 4; ++m)                               \
      AF_[m] = *(const bf16x8*)&smem[(RN_) + aRB + m * 512];                    \
    _Pragma("unroll") for (int m = 0; m < 4; ++m)                               \
      AF_[4 + m] = *(const bf16x8*)&smem[(RN_) + aRB + 4096 + m * 512];         \
  }

#define COMP(AF_, BF_)                                                          \
  {                                                                             \
    __builtin_amdgcn_s_setprio(1);                                              \
    _Pragma("unroll") for (int m = 0; m < 8; ++m)                               \
      _Pragma("unroll") for (int n = 0; n < 4; ++n)                             \
        acc[m][n] = MFMA_BF16(AF_[m], BF_[n], acc[m][n], 0, 0, 0);              \
    __builtin_amdgcn_s_setprio(0);                                              \
  }

// One tile with parity-staggered PREF/COMP order.
#define TILE_STAG(RN_, AFc, BFc, AFn, BFn)                                      \
  if (stag) { COMP(AFc, BFc); PREF(RN_, AFn, BFn); }                            \
  else      { PREF(RN_, AFn, BFn); COMP(AFc, BFc); }

#define WIN_BAR                                                                 \
  asm volatile("s_waitcnt vmcnt(0)" ::: "memory");                              \
  __builtin_amdgcn_s_barrier();

__global__ __launch_bounds__(512, 1)
void lstm_gemm_kernel(const ushort* __restrict__ A, const ushort* __restrict__ Wp,
                      const float* __restrict__ c,
                      const float* __restrict__ bii, const float* __restrict__ bif_,
                      const float* __restrict__ big_, const float* __restrict__ bio_,
                      const float* __restrict__ bhi, const float* __restrict__ bhf,
                      const float* __restrict__ bhg, const float* __restrict__ bho,
                      float* __restrict__ out) {
  __shared__ ushort smem[65536];  // 4 ring bufs x (A 256x32 + B 256x32) = 128 KiB
  const int tid = threadIdx.x;
  const int lane = tid & 63, w = tid >> 6;
  const int wm = w >> 2, wn = w & 3;
  const bool stag = (wm != 0);   // SIMD partner waves (w and w+4) get opposite order

  // bn-major XCD mapping: XCD x owns bn in [x*4, x*4+4) x all 16 bm.
  const int bid = blockIdx.x;
  const int xcd = bid & 7, qq = bid >> 3;
  const int bn = (xcd << 2) | (qq >> 4);
  const int bm = qq & 15;

  const int laneRow = lane & 15, lane16 = lane >> 4;
  const int chunkSwz = lane16 ^ ((laneRow >> 1) & 3);
  const int rdCommon = (laneRow >> 1) * 64 + (laneRow & 1) * 32 + chunkSwz * 8;
  const int aRB = wm * 2048 + rdCommon;            // + ring + miq*4096 + m*512
  const int bRB = 8192 + wn * 1024 + rdCommon;     // + ring + niq*4096 + n*512

  const int lrow = 2 * (lane >> 3) + ((lane >> 2) & 1);
  const int schunk = (lane & 3) ^ ((lane >> 3) & 3);
  const ushort* aS = A + (size_t)(bm * 256 + 16 * w + lrow) * 4096 + schunk * 8;
  const ushort* bS = Wp + (size_t)(bn * 256 + 16 * w + lrow) * 4096 + schunk * 8;
  const int dA = w * 512;
  const int dB = 8192 + w * 512;

  f32x4 acc[8][4];
#pragma unroll
  for (int i = 0; i < 8; i++)
#pragma unroll
    for (int j = 0; j < 4; j++) acc[i][j] = (f32x4){0.f, 0.f, 0.f, 0.f};

  // Prologue: stage tiles 0,1,2; all resident; preload tile 0 fragments.
  STAGE_R(0, 0); STAGE_R(1, 16384); STAGE_R(2, 32768);
  asm volatile("s_waitcnt vmcnt(0)" ::: "memory");
  __builtin_amdgcn_s_barrier();

  bf16x8 afA[8], bfA[4], afB[8], bfB[4];
  PREF(0, afA, bfA);

  // Main: windows of 2 tiles; 2 windows unrolled (slot pattern period).
  // Window k: tile 2k   -> STAGE(2k+3), PREF(2k+1)/COMP(2k)   [cur A, nxt B]
  //           tile 2k+1 -> STAGE(2k+4), PREF(2k+2)/COMP(2k+1) [cur B, nxt A]
  //           vmcnt(0); barrier.
#pragma unroll 1
  for (int k = 0; k < 62; k += 2) {
    const int t0 = 2 * k;
    // window k (even): PREF slots 1,2 ; STAGE slots 3,0
    STAGE_R(t0 + 3, 49152);
    TILE_STAG(16384, afA, bfA, afB, bfB);
    STAGE_R(t0 + 4, 0);
    TILE_STAG(32768, afB, bfB, afA, bfA);
    WIN_BAR;
    // window k+1 (odd): PREF slots 3,0 ; STAGE slots 1,2
    STAGE_R(t0 + 5, 16384);
    TILE_STAG(49152, afA, bfA, afB, bfB);
    STAGE_R(t0 + 6, 32768);
    TILE_STAG(0, afB, bfB, afA, bfA);
    WIN_BAR;
  }

  // Window 62: tiles 124,125. STAGE(127) only. PREF slots 1,2.
  STAGE_R(127, 49152);
  TILE_STAG(16384, afA, bfA, afB, bfB);
  TILE_STAG(32768, afB, bfB, afA, bfA);
  WIN_BAR;
  // Window 63: tiles 126,127. PREF(127) slot 3 at tile 126; no stage.
  TILE_STAG(49152, afA, bfA, afB, bfB);
  COMP(afB, bfB);

  // Fused LSTM epilogue: acc[mi][gate][rr] register-local per (row, hcol).
  const int hcol = bn * 64 + wn * 16 + laneRow;
  const float bI = bii[hcol] + bhi[hcol];
  const float bF = bif_[hcol] + bhf[hcol];
  const float bG = big_[hcol] + bhg[hcol];
  const float bO = bio_[hcol] + bho[hcol];
#pragma unroll
  for (int mi = 0; mi < 8; ++mi) {
    const int rowBase = bm * 256 + (mi >> 2) * 128 + wm * 64 + (mi & 3) * 16 + lane16 * 4;
#pragma unroll
    for (int rr = 0; rr < 4; ++rr) {
      const int row = rowBase + rr;
      const float ii = acc[mi][0][rr] + bI;
      const float ff = acc[mi][1][rr] + bF;
      const float gg = acc[mi][2][rr] + bG;
      const float oo = acc[mi][3][rr] + bO;
      const float iv = 1.f / (1.f + __expf(-ii));
      const float fv = 1.f / (1.f + __expf(-ff));
      const float gv = tanhf(gg);
      const float ov = 1.f / (1.f + __expf(-oo));
      const float cv = c[(size_t)row * 2048 + hcol];
      const float cn = fv * cv + iv * gv;
      const float hn = ov * tanhf(cn);
      out[(size_t)row * 2048 + hcol] = hn;
      out[(size_t)8388608 + (size_t)row * 2048 + hcol] = cn;
    }
  }
}

extern "C" void kernel_launch(void* const* d_in, const int* in_sizes, int n_in,
                              void* d_out, int out_size, void* d_ws, size_t ws_size,
                              hipStream_t stream) {
  const float* x = (const float*)d_in[0];
  const float* h = (const float*)d_in[1];
  const float* c = (const float*)d_in[2];
  const float* Wii = (const float*)d_in[3];  const float* bii = (const float*)d_in[4];
  const float* Wif = (const float*)d_in[5];  const float* bif_ = (const float*)d_in[6];
  const float* Wig = (const float*)d_in[7];  const float* big_ = (const float*)d_in[8];
  const float* Wio = (const float*)d_in[9];  const float* bio_ = (const float*)d_in[10];
  const float* Whi = (const float*)d_in[11]; const float* bhi = (const float*)d_in[12];
  const float* Whf = (const float*)d_in[13]; const float* bhf = (const float*)d_in[14];
  const float* Whg = (const float*)d_in[15]; const float* bhg = (const float*)d_in[16];
  const float* Who = (const float*)d_in[17]; const float* bho = (const float*)d_in[18];

  ushort* Abf = (ushort*)d_ws;                    // 4096*4096 bf16
  ushort* Wpk = Abf + (size_t)4096 * 4096;        // 8192*4096 bf16
  float* out = (float*)d_out;

  pack_all_kernel<<<3072, 256, 0, stream>>>((const float4*)x, (const float4*)h,
                                            Wii, Wif, Wig, Wio, Whi, Whf, Whg, Who,
                                            (ushort4*)Abf, (ushort4*)Wpk);
  lstm_gemm_kernel<<<512, 512, 0, stream>>>(Abf, Wpk, c,
                                            bii, bif_, big_, bio_, bhi, bhf, bhg, bho, out);
}

// Round 10
// 478.537 us; speedup vs baseline: 6.0052x; 6.0052x over previous
//
#include <hip/hip_runtime.h>
#include <stdint.h>

typedef __attribute__((ext_vector_type(4))) float f32x4;
typedef __attribute__((ext_vector_type(8))) short bf16x8;

#define MFMA_BF16 __builtin_amdgcn_mfma_f32_16x16x32_bf16

__device__ __forceinline__ unsigned short f2bf(float f) {
  union { float f; uint32_t u; } a; a.f = f;
  uint32_t u = a.u;
  uint32_t r = (u + 0x7FFFu + ((u >> 16) & 1u)) >> 16;
  return (unsigned short)r;
}

// Merged pack: quads 0..4194303 = A ([x|h] -> bf16 A[4096][4096]);
// quads 4194304..12582911 = W (8 mats -> gate-interleaved Wp[8192][4096]).
// Packed row p (within 256-row bn panel): [half(2)][wn(4)][glow(2)][hlow(16)]
//   gate g = half*2+glow ; hcol H = bn*64 + wn*16 + hlow
__global__ void pack_all_kernel(const float4* __restrict__ x, const float4* __restrict__ hh,
                                const float* __restrict__ Wii, const float* __restrict__ Wif,
                                const float* __restrict__ Wig, const float* __restrict__ Wio,
                                const float* __restrict__ Whi, const float* __restrict__ Whf,
                                const float* __restrict__ Whg, const float* __restrict__ Who,
                                ushort4* __restrict__ A, ushort4* __restrict__ Wp) {
  const int total = 12582912;
  for (int q = blockIdx.x * blockDim.x + threadIdx.x; q < total; q += gridDim.x * blockDim.x) {
    if (q < 4194304) {
      int row = q >> 10, cq = q & 1023;
      float4 v = (cq < 512) ? x[row * 512 + cq] : hh[row * 512 + (cq - 512)];
      ushort4 o; o.x = f2bf(v.x); o.y = f2bf(v.y); o.z = f2bf(v.z); o.w = f2bf(v.w);
      A[q] = o;
    } else {
      int wq = q - 4194304;
      int p = wq >> 10, kq = wq & 1023;
      int r = p & 255;
      int g = ((r >> 7) << 1) | ((r >> 4) & 1);
      int H = ((p >> 8) << 6) | (((r >> 5) & 3) << 4) | (r & 15);
      const float* src;
      if (kq < 512) src = (g == 0) ? Wii : (g == 1) ? Wif : (g == 2) ? Wig : Wio;
      else          src = (g == 0) ? Whi : (g == 1) ? Whf : (g == 2) ? Whg : Who;
      const float4 v = *(const float4*)&src[(size_t)H * 2048 + ((kq & 511) << 2)];
      ushort4 o; o.x = f2bf(v.x); o.y = f2bf(v.y); o.z = f2bf(v.z); o.w = f2bf(v.w);
      Wp[wq] = o;
    }
  }
}

// 256x256 tile, BK=64, 8 waves (2Mx4N), per-wave 128x64, 2 LDS buffers.
// Tile body: ALL 24 fragment ds_reads up front (one burst; compiler emits
// descending counted lgkmcnt so only cluster 0 can stall), 8 STGs for tile
// T+1 into the other buffer, then 4 x 16-MFMA clusters (setprio-wrapped).
// One sync point per tile: vmcnt(0); s_barrier; sched_barrier(0).
// T2 XOR-swizzle (0 conflicts measured), bn-major XCD mapping.
#define STG(srcbase, jj, koff, dstE)                                                        \
  __builtin_amdgcn_global_load_lds(                                                        \
      (const __attribute__((address_space(1))) void*)((srcbase) + (size_t)(jj)*262144 + (koff)), \
      (__attribute__((address_space(3))) void*)(&smem[(dstE) + (jj)*4096]), 16, 0, 0)

#define TILE(bufE_, obufE_, kS_, DO_STAGE)                                                  \
  {                                                                                         \
    bf16x8 af0[4][2], af1[4][2], b01[2][2], b23[2][2];                                      \
    _Pragma("unroll") for (int m = 0; m < 4; ++m) {                                         \
      af0[m][0] = *(const bf16x8*)&smem[(bufE_) + aBase + m * 1024 + colE0];                \
      af0[m][1] = *(const bf16x8*)&smem[(bufE_) + aBase + m * 1024 + colE1];                \
    }                                                                                       \
    _Pragma("unroll") for (int n = 0; n < 2; ++n) {                                         \
      b01[n][0] = *(const bf16x8*)&smem[(bufE_) + bBase + n * 1024 + colE0];                \
      b01[n][1] = *(const bf16x8*)&smem[(bufE_) + bBase + n * 1024 + colE1];                \
      b23[n][0] = *(const bf16x8*)&smem[(bufE_) + bBase + 8192 + n * 1024 + colE0];         \
      b23[n][1] = *(const bf16x8*)&smem[(bufE_) + bBase + 8192 + n * 1024 + colE1];         \
    }                                                                                       \
    _Pragma("unroll") for (int m = 0; m < 4; ++m) {                                         \
      af1[m][0] = *(const bf16x8*)&smem[(bufE_) + aBase + 8192 + m * 1024 + colE0];         \
      af1[m][1] = *(const bf16x8*)&smem[(bufE_) + aBase + 8192 + m * 1024 + colE1];         \
    }                                                                                       \
    if (DO_STAGE) {                                                                         \
      STG(aSrc, 0, kS_, (obufE_) + aDstW); STG(aSrc, 1, kS_, (obufE_) + aDstW);             \
      STG(aSrc, 2, kS_, (obufE_) + aDstW); STG(aSrc, 3, kS_, (obufE_) + aDstW);             \
      STG(bSrc, 0, kS_, (obufE_) + bDstW); STG(bSrc, 1, kS_, (obufE_) + bDstW);             \
      STG(bSrc, 2, kS_, (obufE_) + bDstW); STG(bSrc, 3, kS_, (obufE_) + bDstW);             \
    }                                                                                       \
    __builtin_amdgcn_s_setprio(1);                                                          \
    _Pragma("unroll") for (int m = 0; m < 4; ++m)                                           \
      _Pragma("unroll") for (int n = 0; n < 2; ++n) {                                       \
        acc[m][n] = MFMA_BF16(af0[m][0], b01[n][0], acc[m][n], 0, 0, 0);                    \
        acc[m][n] = MFMA_BF16(af0[m][1], b01[n][1], acc[m][n], 0, 0, 0);                    \
      }                                                                                     \
    _Pragma("unroll") for (int m = 0; m < 4; ++m)                                           \
      _Pragma("unroll") for (int n = 0; n < 2; ++n) {                                       \
        acc[m][2 + n] = MFMA_BF16(af0[m][0], b23[n][0], acc[m][2 + n], 0, 0, 0);            \
        acc[m][2 + n] = MFMA_BF16(af0[m][1], b23[n][1], acc[m][2 + n], 0, 0, 0);            \
      }                                                                                     \
    _Pragma("unroll") for (int m = 0; m < 4; ++m)                                           \
      _Pragma("unroll") for (int n = 0; n < 2; ++n) {                                       \
        acc[4 + m][n] = MFMA_BF16(af1[m][0], b01[n][0], acc[4 + m][n], 0, 0, 0);            \
        acc[4 + m][n] = MFMA_BF16(af1[m][1], b01[n][1], acc[4 + m][n], 0, 0, 0);            \
      }                                                                                     \
    _Pragma("unroll") for (int m = 0; m < 4; ++m)                                           \
      _Pragma("unroll") for (int n = 0; n < 2; ++n) {                                       \
        acc[4 + m][2 + n] = MFMA_BF16(af1[m][0], b23[n][0], acc[4 + m][2 + n], 0, 0, 0);    \
        acc[4 + m][2 + n] = MFMA_BF16(af1[m][1], b23[n][1], acc[4 + m][2 + n], 0, 0, 0);    \
      }                                                                                     \
    __builtin_amdgcn_s_setprio(0);                                                          \
  }

#define TILE_BAR                                                                            \
  asm volatile("s_waitcnt vmcnt(0)" ::: "memory");                                          \
  __builtin_amdgcn_s_barrier();                                                             \
  __builtin_amdgcn_sched_barrier(0);

__global__ __launch_bounds__(512, 2)
void lstm_gemm_kernel(const ushort* __restrict__ A, const ushort* __restrict__ Wp,
                      const float* __restrict__ c,
                      const float* __restrict__ bii, const float* __restrict__ bif_,
                      const float* __restrict__ big_, const float* __restrict__ bio_,
                      const float* __restrict__ bhi, const float* __restrict__ bhf,
                      const float* __restrict__ bhg, const float* __restrict__ bho,
                      float* __restrict__ out) {
  __shared__ ushort smem[65536];  // 2 bufs x (A 256x64 + B 256x64) bf16 = 128 KiB
  const int tid = threadIdx.x;
  const int lane = tid & 63, w = tid >> 6;
  const int wm = w >> 2, wn = w & 3;

  // bn-major XCD mapping: XCD x owns bn in [x*4, x*4+4) x all 16 bm.
  const int bid = blockIdx.x;
  const int xcd = bid & 7, qq = bid >> 3;
  const int bn = (xcd << 2) | (qq >> 4);
  const int bm = qq & 15;

  const int laneRow = lane & 15, lane16 = lane >> 4;
  const int lr7 = laneRow & 7;
  const int colE0 = (lane16 ^ lr7) << 3;         // elem offset within row, kk=0
  const int colE1 = ((4 + lane16) ^ lr7) << 3;   // kk=1

  // Staging: per inst, lane l -> LDS row +(l>>3), phys slot (l&7); slot s at row r
  // holds logical chunk s^(r&7) -> pre-swizzled global source chunk.
  const int srow = w * 8 + (lane >> 3);
  const int chunkOff = ((lane & 7) ^ (lane >> 3)) << 3;
  const ushort* aSrc = A + (size_t)(bm * 256 + srow) * 4096 + chunkOff;
  const ushort* bSrc = Wp + (size_t)(bn * 256 + srow) * 4096 + chunkOff;
  const int aDstW = w * 512;           // + buf + jj*4096
  const int bDstW = 16384 + w * 512;

  const int aBase = (wm * 64 + laneRow) * 64;           // + buf + miq*8192 + m*1024 + colE
  const int bBase = 16384 + (wn * 32 + laneRow) * 64;   // + buf + (ni>>1)*8192 + (ni&1)*1024 + colE

  f32x4 acc[8][4];
#pragma unroll
  for (int i = 0; i < 8; i++)
#pragma unroll
    for (int j = 0; j < 4; j++) acc[i][j] = (f32x4){0.f, 0.f, 0.f, 0.f};

  // Prologue: stage T0 into buf0.
  STG(aSrc, 0, 0, aDstW); STG(aSrc, 1, 0, aDstW);
  STG(aSrc, 2, 0, aDstW); STG(aSrc, 3, 0, aDstW);
  STG(bSrc, 0, 0, bDstW); STG(bSrc, 1, 0, bDstW);
  STG(bSrc, 2, 0, bDstW); STG(bSrc, 3, 0, bDstW);
  TILE_BAR;

  // Steady: 2 tiles per iteration, branch-free (tail peeled).
#pragma unroll 1
  for (int T = 0; T < 62; T += 2) {
    const int k1 = (T + 1) << 6, k2 = (T + 2) << 6;
    TILE(0, 32768, k1, true);
    TILE_BAR;
    TILE(32768, 0, k2, true);
    TILE_BAR;
  }
  // T=62: stage tile 63; T=63: no stage, no trailing sync needed.
  TILE(0, 32768, 63 << 6, true);
  TILE_BAR;
  TILE(32768, 0, 0, false);

  // Fused LSTM epilogue: acc[mi][gate][rr] register-local per (row, hcol).
  const int hcol = bn * 64 + wn * 16 + laneRow;
  const float bI = bii[hcol] + bhi[hcol];
  const float bF = bif_[hcol] + bhf[hcol];
  const float bG = big_[hcol] + bhg[hcol];
  const float bO = bio_[hcol] + bho[hcol];
#pragma unroll
  for (int mi = 0; mi < 8; ++mi) {
    const int rowBase = bm * 256 + (mi >> 2) * 128 + wm * 64 + (mi & 3) * 16 + lane16 * 4;
#pragma unroll
    for (int rr = 0; rr < 4; ++rr) {
      const int row = rowBase + rr;
      const float ii = acc[mi][0][rr] + bI;
      const float ff = acc[mi][1][rr] + bF;
      const float gg = acc[mi][2][rr] + bG;
      const float oo = acc[mi][3][rr] + bO;
      const float iv = 1.f / (1.f + __expf(-ii));
      const float fv = 1.f / (1.f + __expf(-ff));
      const float gv = tanhf(gg);
      const float ov = 1.f / (1.f + __expf(-oo));
      const float cv = c[(size_t)row * 2048 + hcol];
      const float cn = fv * cv + iv * gv;
      const float hn = ov * tanhf(cn);
      out[(size_t)row * 2048 + hcol] = hn;
      out[(size_t)8388608 + (size_t)row * 2048 + hcol] = cn;
    }
  }
}

extern "C" void kernel_launch(void* const* d_in, const int* in_sizes, int n_in,
                              void* d_out, int out_size, void* d_ws, size_t ws_size,
                              hipStream_t stream) {
  const float* x = (const float*)d_in[0];
  const float* h = (const float*)d_in[1];
  const float* c = (const float*)d_in[2];
  const float* Wii = (const float*)d_in[3];  const float* bii = (const float*)d_in[4];
  const float* Wif = (const float*)d_in[5];  const float* bif_ = (const float*)d_in[6];
  const float* Wig = (const float*)d_in[7];  const float* big_ = (const float*)d_in[8];
  const float* Wio = (const float*)d_in[9];  const float* bio_ = (const float*)d_in[10];
  const float* Whi = (const float*)d_in[11]; const float* bhi = (const float*)d_in[12];
  const float* Whf = (const float*)d_in[13]; const float* bhf = (const float*)d_in[14];
  const float* Whg = (const float*)d_in[15]; const float* bhg = (const float*)d_in[16];
  const float* Who = (const float*)d_in[17]; const float* bho = (const float*)d_in[18];

  ushort* Abf = (ushort*)d_ws;                    // 4096*4096 bf16
  ushort* Wpk = Abf + (size_t)4096 * 4096;        // 8192*4096 bf16
  float* out = (float*)d_out;

  pack_all_kernel<<<3072, 256, 0, stream>>>((const float4*)x, (const float4*)h,
                                            Wii, Wif, Wig, Wio, Whi, Whf, Whg, Who,
                                            (ushort4*)Abf, (ushort4*)Wpk);
  lstm_gemm_kernel<<<512, 512, 0, stream>>>(Abf, Wpk, c,
                                            bii, bif_, big_, bio_, bhi, bhf, bhg, bho, out);
}

// Round 11
// 312.665 us; speedup vs baseline: 9.1910x; 1.5305x over previous
//
#include <hip/hip_runtime.h>
#include <stdint.h>

typedef __attribute__((ext_vector_type(4))) float f32x4;
typedef __attribute__((ext_vector_type(8))) short bf16x8;

#define MFMA_BF16 __builtin_amdgcn_mfma_f32_16x16x32_bf16

__device__ __forceinline__ unsigned short f2bf(float f) {
  union { float f; uint32_t u; } a; a.f = f;
  uint32_t u = a.u;
  uint32_t r = (u + 0x7FFFu + ((u >> 16) & 1u)) >> 16;
  return (unsigned short)r;
}

// Merged pack: quads 0..4194303 = A ([x|h] -> bf16 A[4096][4096]);
// quads 4194304..12582911 = W (8 mats -> gate-interleaved Wp[8192][4096]).
// Packed row p (within 256-row bn panel): [half(2)][wn(4)][glow(2)][hlow(16)]
//   gate g = half*2+glow ; hcol H = bn*64 + wn*16 + hlow
__global__ void pack_all_kernel(const float4* __restrict__ x, const float4* __restrict__ hh,
                                const float* __restrict__ Wii, const float* __restrict__ Wif,
                                const float* __restrict__ Wig, const float* __restrict__ Wio,
                                const float* __restrict__ Whi, const float* __restrict__ Whf,
                                const float* __restrict__ Whg, const float* __restrict__ Who,
                                ushort4* __restrict__ A, ushort4* __restrict__ Wp) {
  const int total = 12582912;
  for (int q = blockIdx.x * blockDim.x + threadIdx.x; q < total; q += gridDim.x * blockDim.x) {
    if (q < 4194304) {
      int row = q >> 10, cq = q & 1023;
      float4 v = (cq < 512) ? x[row * 512 + cq] : hh[row * 512 + (cq - 512)];
      ushort4 o; o.x = f2bf(v.x); o.y = f2bf(v.y); o.z = f2bf(v.z); o.w = f2bf(v.w);
      A[q] = o;
    } else {
      int wq = q - 4194304;
      int p = wq >> 10, kq = wq & 1023;
      int r = p & 255;
      int g = ((r >> 7) << 1) | ((r >> 4) & 1);
      int H = ((p >> 8) << 6) | (((r >> 5) & 3) << 4) | (r & 15);
      const float* src;
      if (kq < 512) src = (g == 0) ? Wii : (g == 1) ? Wif : (g == 2) ? Wig : Wio;
      else          src = (g == 0) ? Whi : (g == 1) ? Whf : (g == 2) ? Whg : Who;
      const float4 v = *(const float4*)&src[(size_t)H * 2048 + ((kq & 511) << 2)];
      ushort4 o; o.x = f2bf(v.x); o.y = f2bf(v.y); o.z = f2bf(v.z); o.w = f2bf(v.w);
      Wp[wq] = o;
    }
  }
}

// Faithful m201 8-phase port. 256x256 tile, BK=64, 8 waves (2Mx4N), per-wave
// 128x64. LDS: 2 bufs x {A0,A1,B0,B1} half-tiles ([128][64] bf16 each).
// Per phase: {ds-reads for THIS quadrant; stage ONE half-tile (2 gloads);
// [lgkmcnt(8) if 12 reads]; barrier; lgkmcnt(0); setprio1; 16 MFMA; setprio0;
// barrier}. vmcnt(6) once per K-tile at tile end. No sched_barrier.
#define BAR __builtin_amdgcn_s_barrier()
#define LGKM0 asm volatile("s_waitcnt lgkmcnt(0)" ::: "memory")

#define STGH(srcH, kOff, dstE)                                                  \
  __builtin_amdgcn_global_load_lds(                                             \
      (const __attribute__((address_space(1))) void*)((srcH) + (kOff)),         \
      (__attribute__((address_space(3))) void*)(&smem[dstE]), 16, 0, 0);        \
  __builtin_amdgcn_global_load_lds(                                             \
      (const __attribute__((address_space(1))) void*)((srcH) + 32768 + (kOff)), \
      (__attribute__((address_space(3))) void*)(&smem[(dstE) + 512]), 16, 0, 0)

// ENDM: 0 = vmcnt(6)+bar (steady), 1 = vmcnt(0)+bar (T=62), 2 = none (T=63)
#define TILE8(bufE_, nbufE_, kA1_, kT2_, ST_A1, ST_T2, ENDM)                       \
  {                                                                                \
    bf16x8 af0[4][2], af1[4][2], b01[2][2], b23[2][2];                             \
    /* -- ph0: reads af0+b01 (12); stage A1(T+1)->nbuf; q00 -- */                  \
    _Pragma("unroll") for (int m = 0; m < 4; ++m) {                                \
      af0[m][0] = *(const bf16x8*)&smem[(bufE_) + aR + m * 1024 + colE0];          \
      af0[m][1] = *(const bf16x8*)&smem[(bufE_) + aR + m * 1024 + colE1];          \
    }                                                                              \
    _Pragma("unroll") for (int n = 0; n < 2; ++n) {                                \
      b01[n][0] = *(const bf16x8*)&smem[(bufE_) + 16384 + bR + n * 1024 + colE0];  \
      b01[n][1] = *(const bf16x8*)&smem[(bufE_) + 16384 + bR + n * 1024 + colE1];  \
    }                                                                              \
    if (ST_A1) { STGH(aSrcH1, kA1_, (nbufE_) + 8192 + dstW); }                     \
    asm volatile("s_waitcnt lgkmcnt(8)" ::: "memory");                             \
    BAR; LGKM0;                                                                    \
    __builtin_amdgcn_s_setprio(1);                                                 \
    _Pragma("unroll") for (int m = 0; m < 4; ++m)                                  \
      _Pragma("unroll") for (int n = 0; n < 2; ++n) {                              \
        acc[m][n] = MFMA_BF16(af0[m][0], b01[n][0], acc[m][n], 0, 0, 0);           \
        acc[m][n] = MFMA_BF16(af0[m][1], b01[n][1], acc[m][n], 0, 0, 0);           \
      }                                                                            \
    __builtin_amdgcn_s_setprio(0);                                                 \
    BAR;                                                                           \
    /* -- ph1: reads b23 (4); stage A0(T+2)->buf; q01 -- */                        \
    _Pragma("unroll") for (int n = 0; n < 2; ++n) {                                \
      b23[n][0] = *(const bf16x8*)&smem[(bufE_) + 24576 + bR + n * 1024 + colE0];  \
      b23[n][1] = *(const bf16x8*)&smem[(bufE_) + 24576 + bR + n * 1024 + colE1];  \
    }                                                                              \
    if (ST_T2) { STGH(aSrcH0, kT2_, (bufE_) + dstW); }                             \
    BAR; LGKM0;                                                                    \
    __builtin_amdgcn_s_setprio(1);                                                 \
    _Pragma("unroll") for (int m = 0; m < 4; ++m)                                  \
      _Pragma("unroll") for (int n = 0; n < 2; ++n) {                              \
        acc[m][2 + n] = MFMA_BF16(af0[m][0], b23[n][0], acc[m][2 + n], 0, 0, 0);   \
        acc[m][2 + n] = MFMA_BF16(af0[m][1], b23[n][1], acc[m][2 + n], 0, 0, 0);   \
      }                                                                            \
    __builtin_amdgcn_s_setprio(0);                                                 \
    BAR;                                                                           \
    /* -- ph2: reads af1 (8); stage B0(T+2)->buf; q10 -- */                        \
    _Pragma("unroll") for (int m = 0; m < 4; ++m) {                                \
      af1[m][0] = *(const bf16x8*)&smem[(bufE_) + 8192 + aR + m * 1024 + colE0];   \
      af1[m][1] = *(const bf16x8*)&smem[(bufE_) + 8192 + aR + m * 1024 + colE1];   \
    }                                                                              \
    if (ST_T2) { STGH(bSrcH0, kT2_, (bufE_) + 16384 + dstW); }                     \
    BAR; LGKM0;                                                                    \
    __builtin_amdgcn_s_setprio(1);                                                 \
    _Pragma("unroll") for (int m = 0; m < 4; ++m)                                  \
      _Pragma("unroll") for (int n = 0; n < 2; ++n) {                              \
        acc[4 + m][n] = MFMA_BF16(af1[m][0], b01[n][0], acc[4 + m][n], 0, 0, 0);   \
        acc[4 + m][n] = MFMA_BF16(af1[m][1], b01[n][1], acc[4 + m][n], 0, 0, 0);   \
      }                                                                            \
    __builtin_amdgcn_s_setprio(0);                                                 \
    BAR;                                                                           \
    /* -- ph3: no reads; stage B1(T+2)->buf; q11; tile-end vmcnt -- */             \
    if (ST_T2) { STGH(bSrcH1, kT2_, (bufE_) + 24576 + dstW); }                     \
    BAR;                                                                           \
    __builtin_amdgcn_s_setprio(1);                                                 \
    _Pragma("unroll") for (int m = 0; m < 4; ++m)                                  \
      _Pragma("unroll") for (int n = 0; n < 2; ++n) {                              \
        acc[4 + m][2 + n] = MFMA_BF16(af1[m][0], b23[n][0], acc[4 + m][2 + n], 0, 0, 0); \
        acc[4 + m][2 + n] = MFMA_BF16(af1[m][1], b23[n][1], acc[4 + m][2 + n], 0, 0, 0); \
      }                                                                            \
    __builtin_amdgcn_s_setprio(0);                                                 \
    if ((ENDM) == 0) { asm volatile("s_waitcnt vmcnt(6)" ::: "memory"); BAR; }     \
    else if ((ENDM) == 1) { asm volatile("s_waitcnt vmcnt(0)" ::: "memory"); BAR; } \
  }

__global__ __launch_bounds__(512, 2)
void lstm_gemm_kernel(const ushort* __restrict__ A, const ushort* __restrict__ Wp,
                      const float* __restrict__ c,
                      const float* __restrict__ bii, const float* __restrict__ bif_,
                      const float* __restrict__ big_, const float* __restrict__ bio_,
                      const float* __restrict__ bhi, const float* __restrict__ bhf,
                      const float* __restrict__ bhg, const float* __restrict__ bho,
                      float* __restrict__ out) {
  __shared__ ushort smem[65536];  // 2 bufs x {A0,A1,B0,B1} halves x 16 KiB = 128 KiB
  const int tid = threadIdx.x;
  const int lane = tid & 63, w = tid >> 6;
  const int wm = w >> 2, wn = w & 3;

  // bn-major XCD mapping: XCD x owns bn in [x*4, x*4+4) x all 16 bm.
  const int bid = blockIdx.x;
  const int xcd = bid & 7, qq = bid >> 3;
  const int bn = (xcd << 2) | (qq >> 4);
  const int bm = qq & 15;

  const int laneRow = lane & 15, lane16 = lane >> 4;
  const int lr7 = laneRow & 7;
  const int colE0 = (lane16 ^ lr7) << 3;         // elem offset within 64-el row, kk=0
  const int colE1 = ((4 + lane16) ^ lr7) << 3;   // kk=1

  // DMA: lane l -> half-row (l>>3), phys chunk l&7 holding logical chunk
  // (l&7)^((l>>3)&7) -> pre-swizzled global source (proven 0-conflict scheme).
  const int chunkOff = ((lane & 7) ^ (lane >> 3)) << 3;
  const ushort* aSrcH0 = A + (size_t)(bm * 256 + 16 * w + (lane >> 3)) * 4096 + chunkOff;
  const ushort* aSrcH1 = aSrcH0 + (size_t)128 * 4096;
  const ushort* bSrcH0 = Wp + (size_t)(bn * 256 + 16 * w + (lane >> 3)) * 4096 + chunkOff;
  const ushort* bSrcH1 = bSrcH0 + (size_t)128 * 4096;
  const int dstW = w * 1024;  // wave's 16 rows within a half

  const int aR = (wm * 64 + laneRow) * 64;   // + buf + half + m*1024 + colE
  const int bR = (wn * 32 + laneRow) * 64;   // + buf + half + n*1024 + colE

  f32x4 acc[8][4];
#pragma unroll
  for (int i = 0; i < 8; i++)
#pragma unroll
    for (int j = 0; j < 4; j++) acc[i][j] = (f32x4){0.f, 0.f, 0.f, 0.f};

  // Prologue: 7 halves = steady-state fill. vmcnt(6) -> tile0's 4 halves done.
  STGH(aSrcH0, 0, dstW);                  // A0(0)
  STGH(bSrcH0, 0, 16384 + dstW);          // B0(0)
  STGH(bSrcH1, 0, 24576 + dstW);          // B1(0)
  STGH(aSrcH1, 0, 8192 + dstW);           // A1(0)
  STGH(aSrcH0, 64, 32768 + dstW);         // A0(1)
  STGH(bSrcH0, 64, 32768 + 16384 + dstW); // B0(1)
  STGH(bSrcH1, 64, 32768 + 24576 + dstW); // B1(1)
  asm volatile("s_waitcnt vmcnt(6)" ::: "memory");
  BAR;

#pragma unroll 1
  for (int T = 0; T < 62; T += 2) {
    const int kA = (T + 1) << 6, kB = (T + 2) << 6, kC = (T + 3) << 6;
    TILE8(0, 32768, kA, kB, true, true, 0);
    TILE8(32768, 0, kB, kC, true, true, 0);
  }
  TILE8(0, 32768, 63 << 6, 0, true, false, 1);   // T=62
  TILE8(32768, 0, 0, 0, false, false, 2);        // T=63

  // Fused LSTM epilogue: acc[mi][gate][rr] register-local per (row, hcol).
  const int hcol = bn * 64 + wn * 16 + laneRow;
  const float bI = bii[hcol] + bhi[hcol];
  const float bF = bif_[hcol] + bhf[hcol];
  const float bG = big_[hcol] + bhg[hcol];
  const float bO = bio_[hcol] + bho[hcol];
#pragma unroll
  for (int mi = 0; mi < 8; ++mi) {
    const int rowBase = bm * 256 + (mi >> 2) * 128 + wm * 64 + (mi & 3) * 16 + lane16 * 4;
#pragma unroll
    for (int rr = 0; rr < 4; ++rr) {
      const int row = rowBase + rr;
      const float ii = acc[mi][0][rr] + bI;
      const float ff = acc[mi][1][rr] + bF;
      const float gg = acc[mi][2][rr] + bG;
      const float oo = acc[mi][3][rr] + bO;
      const float iv = 1.f / (1.f + __expf(-ii));
      const float fv = 1.f / (1.f + __expf(-ff));
      const float gv = tanhf(gg);
      const float ov = 1.f / (1.f + __expf(-oo));
      const float cv = c[(size_t)row * 2048 + hcol];
      const float cn = fv * cv + iv * gv;
      const float hn = ov * tanhf(cn);
      out[(size_t)row * 2048 + hcol] = hn;
      out[(size_t)8388608 + (size_t)row * 2048 + hcol] = cn;
    }
  }
}

extern "C" void kernel_launch(void* const* d_in, const int* in_sizes, int n_in,
                              void* d_out, int out_size, void* d_ws, size_t ws_size,
                              hipStream_t stream) {
  const float* x = (const float*)d_in[0];
  const float* h = (const float*)d_in[1];
  const float* c = (const float*)d_in[2];
  const float* Wii = (const float*)d_in[3];  const float* bii = (const float*)d_in[4];
  const float* Wif = (const float*)d_in[5];  const float* bif_ = (const float*)d_in[6];
  const float* Wig = (const float*)d_in[7];  const float* big_ = (const float*)d_in[8];
  const float* Wio = (const float*)d_in[9];  const float* bio_ = (const float*)d_in[10];
  const float* Whi = (const float*)d_in[11]; const float* bhi = (const float*)d_in[12];
  const float* Whf = (const float*)d_in[13]; const float* bhf = (const float*)d_in[14];
  const float* Whg = (const float*)d_in[15]; const float* bhg = (const float*)d_in[16];
  const float* Who = (const float*)d_in[17]; const float* bho = (const float*)d_in[18];

  ushort* Abf = (ushort*)d_ws;                    // 4096*4096 bf16
  ushort* Wpk = Abf + (size_t)4096 * 4096;        // 8192*4096 bf16
  float* out = (float*)d_out;

  pack_all_kernel<<<3072, 256, 0, stream>>>((const float4*)x, (const float4*)h,
                                            Wii, Wif, Wig, Wio, Whi, Whf, Whg, Who,
                                            (ushort4*)Abf, (ushort4*)Wpk);
  lstm_gemm_kernel<<<512, 512, 0, stream>>>(Abf, Wpk, c,
                                            bii, bif_, big_, bio_, bhi, bhf, bhg, bho, out);
}